// Round 6
// baseline (8188.438 us; speedup 1.0000x reference)
//
#include <hip/hip_runtime.h>
#include <stdint.h>

#define F_DIM 512
#define CAP   64
#define MAXV  9216
#define GD    4
#define ROWD  512   // dwords per adjacency-bitset row (2048 B)

typedef unsigned long long u64;

// ---------------- per-vertex squared norm (fp64 accumulate) ----------------
__global__ void k_sq(const float* __restrict__ img, double* __restrict__ sqd, int V) {
  int v = blockIdx.x;
  if (v >= V) return;
  const float* row = img + (size_t)v * F_DIM;
  double s = 0.0;
  for (int f = threadIdx.x; f < F_DIM; f += 64) {
    double x = (double)row[f];
    s += x * x;
  }
  for (int off = 32; off > 0; off >>= 1) s += __shfl_down(s, off);
  if (threadIdx.x == 0) sqd[v] = s;
}

// ---------------- edge eligibility (boundary test) -------------------------
__global__ void k_prep(const float* __restrict__ vs, const int* __restrict__ edges,
                       int E, unsigned char* __restrict__ elig) {
  int i = blockIdx.x * blockDim.x + threadIdx.x;
  if (i < E) {
    int a = edges[i], b = edges[E + i];
    float ax = vs[2 * a], ay = vs[2 * a + 1];
    float bx = vs[2 * b], by = vs[2 * b + 1];
    const float eps = 1e-3f;
    const float hi = 1.0f - 1e-3f;
    bool ba = (ax < eps) || (ax > hi) || (ay < eps) || (ay > hi);
    bool bb = (bx < eps) || (bx > hi) || (by < eps) || (by > hi);
    elig[i] = (!ba && !bb) ? 1 : 0;
  }
}

// ---------------- sortable keys: prio(double) top bits | edge id -----------
__global__ void k_keys(const double* __restrict__ sqd, const int* __restrict__ edges,
                       int E, int P, u64* __restrict__ keys) {
  int e = blockIdx.x * blockDim.x + threadIdx.x;
  if (e >= P) return;
  if (e < E) {
    double prio = sqd[edges[e]] + sqd[edges[E + e]];
    u64 bits = (u64)__double_as_longlong(prio);  // prio > 0 -> bits monotone
    keys[e] = (bits & ~0xFFFFull) | (u64)e;
  } else {
    keys[e] = ~0ull;
  }
}

// ---------------- single-block bitonic sort, LDS-staged --------------------
#define SCH 4096
__global__ void __launch_bounds__(1024)
k_sort(u64* __restrict__ keys, int n) {
  __shared__ u64 buf[SCH];
  int tid = threadIdx.x;
  int nt = blockDim.x;
  int ch = n < SCH ? n : SCH;
  for (int chunk = 0; chunk < n; chunk += ch) {
    for (int i = tid; i < ch; i += nt) buf[i] = keys[chunk + i];
    __syncthreads();
    for (int k = 2; k <= ch; k <<= 1) {
      for (int j = k >> 1; j > 0; j >>= 1) {
        for (int li = tid; li < ch; li += nt) {
          int lj = li ^ j;
          if (lj > li) {
            u64 x = buf[li], y = buf[lj];
            bool up = (((chunk + li) & k) == 0);
            if (up ? (x > y) : (x < y)) { buf[li] = y; buf[lj] = x; }
          }
        }
        __syncthreads();
      }
    }
    for (int i = tid; i < ch; i += nt) keys[chunk + i] = buf[i];
    __syncthreads();
  }
  for (int k = (ch << 1); k <= n; k <<= 1) {
    for (int j = k >> 1; j >= ch; j >>= 1) {
      for (int i = tid; i < n; i += nt) {
        int ixj = i ^ j;
        if (ixj > i) {
          u64 x = keys[i], y = keys[ixj];
          bool up = ((i & k) == 0);
          if (up ? (x > y) : (x < y)) { keys[i] = y; keys[ixj] = x; }
        }
      }
      __syncthreads();
    }
    for (int chunk = 0; chunk < n; chunk += ch) {
      for (int i = tid; i < ch; i += nt) buf[i] = keys[chunk + i];
      __syncthreads();
      for (int j = ch >> 1; j > 0; j >>= 1) {
        for (int li = tid; li < ch; li += nt) {
          int lj = li ^ j;
          if (lj > li) {
            u64 x = buf[li], y = buf[lj];
            bool up = (((chunk + li) & k) == 0);
            if (up ? (x > y) : (x < y)) { buf[li] = y; buf[lj] = x; }
          }
        }
        __syncthreads();
      }
      for (int i = tid; i < ch; i += nt) keys[chunk + i] = buf[i];
      __syncthreads();
    }
  }
}

// ---------------- gather sorted (v0,v1,elig) into one packed word ----------
__global__ void k_reorder(const u64* __restrict__ keys, const int* __restrict__ edges,
                          const unsigned char* __restrict__ elig, int E,
                          unsigned* __restrict__ packed) {
  int t = blockIdx.x * blockDim.x + threadIdx.x;
  if (t >= E) return;
  int eid = (int)(keys[t] & 0xFFFFull);
  unsigned v0 = (unsigned)edges[eid];
  unsigned v1 = (unsigned)edges[E + eid];
  unsigned el = (unsigned)elig[eid];
  packed[t] = v0 | (v1 << 14) | (el << 28);
}

// ---------------- build adjacency bitsets (rows live in d_out) -------------
__global__ void k_bs_build(const int* __restrict__ edges, int E, unsigned* __restrict__ bs) {
  int e = blockIdx.x * blockDim.x + threadIdx.x;
  if (e >= E) return;
  int a = edges[e], b = edges[E + e];
  atomicOr(bs + (size_t)a * ROWD + (b >> 5), 1u << (b & 31));
  atomicOr(bs + (size_t)b * ROWD + (a >> 5), 1u << (a & 31));
}

// ---------------- sequential greedy decimation (single wave) ---------------
// Exact adjacency bitsets (dense over V). Eval: AND + popcount + ballots.
// Commit: overwrite bs[v0] with merged set; atomics fix rows of N(v1).
// mark[v] in LDS: 0xFFFF = dead; else seq of last modifying commit.
// A prefetched row copy is valid iff mark[row] <= lastDrain at load time;
// otherwise vmcnt(0)-drain + reload (rare).
__global__ void __launch_bounds__(64, 1)
k_decimate(int E, int V, int target, const unsigned* __restrict__ packed,
           unsigned* __restrict__ bs, int2* __restrict__ events, int* __restrict__ nev_out) {
  __shared__ unsigned short mark[MAXV];
  const int lane = threadIdx.x;
  if (V > MAXV) return;
  for (int v = lane; v < V; v += 64) mark[v] = 0;
  __syncthreads();

  int count = V, nev = 0, lastDrain = 0;
  bool stop = false;
  u64 cm = 0;
  unsigned pk = 0;

  auto clrBit = [&](uint4& r0, uint4& r1, int v) {
    int d = v >> 5;
    int c = d >> 8, rr = d & 255, l = rr >> 2, k = rr & 3;
    unsigned m = ~(1u << (v & 31));
    if (lane == l) {
      if (c == 0) {
        if (k == 0) r0.x &= m; else if (k == 1) r0.y &= m;
        else if (k == 2) r0.z &= m; else r0.w &= m;
      } else {
        if (k == 0) r1.x &= m; else if (k == 1) r1.y &= m;
        else if (k == 2) r1.z &= m; else r1.w &= m;
      }
    }
  };

  auto scanW = [&](unsigned w, int dbase, int cv0, unsigned w0, unsigned sb0,
                   unsigned w1, unsigned cb1, unsigned short seq) {
    while (w) {
      int b = __builtin_ctz(w); w &= w - 1;
      int u = (dbase << 5) + b;
      if (u != cv0) {
        unsigned* ru = bs + (size_t)u * ROWD;
        atomicAnd(ru + w1, cb1);  // clear v1 bit
        atomicOr(ru + w0, sb0);   // set v0 bit
        mark[u] = seq;
      }
    }
  };

  auto pick = [&](int* v0, int* v1) -> bool {
    bool any = false;
#pragma unroll
    for (int g = 0; g < GD; ++g) {
      v0[g] = -1; v1[g] = -1;
      if (cm) {
        int idx = __builtin_ctzll(cm); cm &= cm - 1;
        unsigned pkc = __builtin_amdgcn_readlane(pk, idx);
        v0[g] = (int)(pkc & 0x3FFFu);
        v1[g] = (int)((pkc >> 14) & 0x3FFFu);
        any = true;
      }
    }
    return any;
  };

  auto load = [&](const int* v0, const int* v1, uint4* a0, uint4* a1,
                  uint4* b0, uint4* b1, int& LD) {
    LD = lastDrain;
#pragma unroll
    for (int g = 0; g < GD; ++g) {
      if (v0[g] >= 0) {
        const uint4* pa = (const uint4*)(bs + (size_t)v0[g] * ROWD);
        a0[g] = pa[lane]; a1[g] = pa[lane + 64];
        const uint4* pb = (const uint4*)(bs + (size_t)v1[g] * ROWD);
        b0[g] = pb[lane]; b1[g] = pb[lane + 64];
      }
    }
  };

  auto proc = [&](const int* v0a, const int* v1a, uint4* a0, uint4* a1,
                  uint4* b0, uint4* b1, int LD) {
#pragma unroll
    for (int g = 0; g < GD; ++g) {
      int cv0 = v0a[g], cv1 = v1a[g];
      if (cv0 < 0 || stop) continue;
      int s0 = mark[cv0], s1 = mark[cv1];
      if (s0 == 0xFFFF || s1 == 0xFFFF) continue;   // endpoint dead
      if (s0 > LD || s1 > LD) {
        // register copy predates a modification: drain atomics + reload
        asm volatile("s_waitcnt vmcnt(0)" ::: "memory");
        __builtin_amdgcn_sched_barrier(0);
        lastDrain = nev;
        const uint4* pa = (const uint4*)(bs + (size_t)cv0 * ROWD);
        a0[g] = pa[lane]; a1[g] = pa[lane + 64];
        const uint4* pb = (const uint4*)(bs + (size_t)cv1 * ROWD);
        b0[g] = pb[lane]; b1[g] = pb[lane + 64];
      }
      uint4 A0 = a0[g], A1 = a1[g], B0 = b0[g], B1 = b1[g];
      int p = __popc(A0.x & B0.x) + __popc(A0.y & B0.y) +
              __popc(A0.z & B0.z) + __popc(A0.w & B0.w) +
              __popc(A1.x & B1.x) + __popc(A1.y & B1.y) +
              __popc(A1.z & B1.z) + __popc(A1.w & B1.w);
      u64 m1 = __ballot(p == 1);
      u64 m2 = __ballot(p == 2);
      u64 m3 = __ballot(p >= 3);
      bool ok = (m3 == 0ull) && ((m2 == 0ull && __popcll(m1) == 2) ||
                                 (m1 == 0ull && __popcll(m2) == 1));
      if (!ok) continue;

      // ---- commit merge cv1 -> cv0 ----
      unsigned short seq = (unsigned short)(nev + 1);
      uint4 M0, M1;
      M0.x = A0.x | B0.x; M0.y = A0.y | B0.y; M0.z = A0.z | B0.z; M0.w = A0.w | B0.w;
      M1.x = A1.x | B1.x; M1.y = A1.y | B1.y; M1.z = A1.z | B1.z; M1.w = A1.w | B1.w;
      clrBit(M0, M1, cv0);
      clrBit(M0, M1, cv1);
      uint4* pv = (uint4*)(bs + (size_t)cv0 * ROWD);
      pv[lane] = M0; pv[lane + 64] = M1;

      unsigned w0 = (unsigned)(cv0 >> 5), sb0 = 1u << (cv0 & 31);
      unsigned w1 = (unsigned)(cv1 >> 5), cb1 = ~(1u << (cv1 & 31));
      int dl = lane << 2;
      scanW(B0.x, dl + 0, cv0, w0, sb0, w1, cb1, seq);
      scanW(B0.y, dl + 1, cv0, w0, sb0, w1, cb1, seq);
      scanW(B0.z, dl + 2, cv0, w0, sb0, w1, cb1, seq);
      scanW(B0.w, dl + 3, cv0, w0, sb0, w1, cb1, seq);
      scanW(B1.x, 256 + dl + 0, cv0, w0, sb0, w1, cb1, seq);
      scanW(B1.y, 256 + dl + 1, cv0, w0, sb0, w1, cb1, seq);
      scanW(B1.z, 256 + dl + 2, cv0, w0, sb0, w1, cb1, seq);
      scanW(B1.w, 256 + dl + 3, cv0, w0, sb0, w1, cb1, seq);

      if (lane == 0) {
        mark[cv1] = 0xFFFF;
        mark[cv0] = seq;
        events[nev] = make_int2(cv0, cv1);
      }
      asm volatile("s_waitcnt lgkmcnt(0)" ::: "memory");
      __builtin_amdgcn_sched_barrier(0);
      nev++;
      count--;
      if (count <= target) stop = true;
    }
  };

  int Av0[GD], Av1[GD], Bv0[GD], Bv1[GD];
  uint4 Aa0[GD], Aa1[GD], Ab0[GD], Ab1[GD];
  uint4 Ba0[GD], Ba1[GD], Bb0[GD], Bb1[GD];
  int ALD, BLD;

  for (int base = 0; base < E && !stop; base += 64) {
    int t = base + lane;
    pk = (t < E) ? packed[t] : 0u;
    int mv0 = (int)(pk & 0x3FFFu);
    int mv1 = (int)((pk >> 14) & 0x3FFFu);
    asm volatile("s_waitcnt lgkmcnt(0)" ::: "memory");
    __builtin_amdgcn_sched_barrier(0);
    bool cand = (t < E) && ((pk >> 28) & 1u) &&
                (mark[mv0] != 0xFFFF) && (mark[mv1] != 0xFFFF);
    cm = __ballot(cand);
    if (!cm) continue;

    bool anyA = pick(Av0, Av1);
    if (anyA) load(Av0, Av1, Aa0, Aa1, Ab0, Ab1, ALD);
    while (anyA && !stop) {
      bool anyB = pick(Bv0, Bv1);
      if (anyB) load(Bv0, Bv1, Ba0, Ba1, Bb0, Bb1, BLD);
      proc(Av0, Av1, Aa0, Aa1, Ab0, Ab1, ALD);
      if (stop || !anyB) break;
      anyA = pick(Av0, Av1);
      if (anyA) load(Av0, Av1, Aa0, Aa1, Ab0, Ab1, ALD);
      proc(Bv0, Bv1, Ba0, Ba1, Bb0, Bb1, BLD);
    }
  }
  if (lane == 0) nev_out[0] = nev;
}

// ---------------- reverse-replay: owner + weight per original vertex -------
__global__ void __launch_bounds__(256)
k_weights(const int2* __restrict__ events, const int* __restrict__ nev_p,
          int V, int* __restrict__ own, float* __restrict__ wgt) {
  __shared__ int O[MAXV];
  __shared__ unsigned short H[MAXV];
  __shared__ int2 evb[256];
  int tid = threadIdx.x;
  if (V > MAXV) return;
  for (int v = tid; v < V; v += blockDim.x) { O[v] = v; H[v] = 0; }
  int n = nev_p[0];
  __syncthreads();
  int nb = (n + 255) >> 8;
  for (int b = nb - 1; b >= 0; --b) {
    int bbase = b << 8;
    int cnt = n - bbase; if (cnt > 256) cnt = 256;
    if (tid < cnt) evb[tid] = events[bbase + tid];
    __syncthreads();
    if (tid == 0) {
      for (int k = cnt - 1; k >= 0; --k) {
        int2 ev = evb[k];
        int h = (int)H[ev.x] + 1;
        H[ev.x] = (unsigned short)h;
        H[ev.y] = (unsigned short)h;
        O[ev.y] = O[ev.x];
      }
    }
    __syncthreads();
  }
  for (int v = tid; v < V; v += blockDim.x) {
    own[v] = O[v];
    wgt[v] = ldexpf(1.0f, -(int)H[v]);
  }
}

// ---------------- output ---------------------------------------------------
__global__ void k_zero(float4* __restrict__ out, int n4) {
  int i = blockIdx.x * blockDim.x + threadIdx.x;
  if (i < n4) out[i] = make_float4(0.f, 0.f, 0.f, 0.f);
}

__global__ void k_scatter(const float* __restrict__ img, const int* __restrict__ own,
                          const float* __restrict__ wgt, float* __restrict__ out, int V) {
  int v = blockIdx.x;
  if (v >= V) return;
  float w = wgt[v];
  int o = own[v];
  const float* src = img + (size_t)v * F_DIM;
  float* dst = out + (size_t)o * F_DIM;
  if (w == 1.0f) {
    for (int f = threadIdx.x; f < F_DIM; f += blockDim.x) dst[f] = src[f];
  } else {
    for (int f = threadIdx.x; f < F_DIM; f += blockDim.x) atomicAdd(&dst[f], w * src[f]);
  }
}

extern "C" void kernel_launch(void* const* d_in, const int* in_sizes, int n_in,
                              void* d_out, int out_size, void* d_ws, size_t ws_size,
                              hipStream_t stream) {
  const float* img  = (const float*)d_in[0];
  const int* edges  = (const int*)d_in[1];
  const float* vs   = (const float*)d_in[2];
  int V = in_sizes[2] / 2;
  int E = in_sizes[1] / 2;
  int P = 1; while (P < E) P <<= 1;

  char* wsp = (char*)d_ws;
  size_t off = 0;
  auto alloc = [&](size_t bytes) -> void* {
    void* p = (void*)(wsp + off);
    off = (off + bytes + 255) & ~(size_t)255;
    return p;
  };
  double* sqd          = (double*)alloc((size_t)V * 8);
  u64* keys            = (u64*)alloc((size_t)P * 8);
  unsigned char* elig  = (unsigned char*)alloc((size_t)E);
  unsigned* packed     = (unsigned*)alloc((size_t)E * 4);
  int2* events         = (int2*)alloc((size_t)(V / 2 + 64) * 8);
  int* nev             = (int*)alloc(256);
  int* own             = (int*)alloc((size_t)V * 4);
  float* wgt           = (float*)alloc((size_t)V * 4);

  unsigned* bs = (unsigned*)d_out;   // 9216 rows x 2048 B == out buffer exactly
  int n4 = (V * F_DIM) / 4;

  hipLaunchKernelGGL(k_sq, dim3(V), dim3(64), 0, stream, img, sqd, V);
  hipLaunchKernelGGL(k_prep, dim3((E + 255) / 256), dim3(256), 0, stream, vs, edges, E, elig);
  hipLaunchKernelGGL(k_keys, dim3((P + 255) / 256), dim3(256), 0, stream, sqd, edges, E, P, keys);
  hipLaunchKernelGGL(k_sort, dim3(1), dim3(1024), 0, stream, keys, P);
  hipLaunchKernelGGL(k_reorder, dim3((E + 255) / 256), dim3(256), 0, stream, keys, edges, elig, E, packed);
  hipLaunchKernelGGL(k_zero, dim3((n4 + 255) / 256), dim3(256), 0, stream, (float4*)d_out, n4);
  hipLaunchKernelGGL(k_bs_build, dim3((E + 255) / 256), dim3(256), 0, stream, edges, E, bs);
  hipLaunchKernelGGL(k_decimate, dim3(1), dim3(64), 0, stream,
                     E, V, V / 2, packed, bs, events, nev);
  hipLaunchKernelGGL(k_weights, dim3(1), dim3(256), 0, stream, events, nev, V, own, wgt);
  hipLaunchKernelGGL(k_zero, dim3((n4 + 255) / 256), dim3(256), 0, stream, (float4*)d_out, n4);
  hipLaunchKernelGGL(k_scatter, dim3(V), dim3(256), 0, stream, img, own, wgt, (float*)d_out, V);
}

// Round 7
// 7502.334 us; speedup vs baseline: 1.0915x; 1.0915x over previous
//
#include <hip/hip_runtime.h>
#include <stdint.h>

#define F_DIM 512
#define CAP   64
#define MAXV  9216
#define GD    8

typedef unsigned long long u64;

// ---------------- per-vertex squared norm (fp64 accumulate) ----------------
__global__ void k_sq(const float* __restrict__ img, double* __restrict__ sqd, int V) {
  int v = blockIdx.x;
  if (v >= V) return;
  const float* row = img + (size_t)v * F_DIM;
  double s = 0.0;
  for (int f = threadIdx.x; f < F_DIM; f += 64) {
    double x = (double)row[f];
    s += x * x;
  }
  for (int off = 32; off > 0; off >>= 1) s += __shfl_down(s, off);
  if (threadIdx.x == 0) sqd[v] = s;
}

// ---------------- zero degrees + edge eligibility (boundary test) ----------
__global__ void k_prep(const float* __restrict__ vs, const int* __restrict__ edges,
                       int V, int E, int* __restrict__ deg, unsigned char* __restrict__ elig) {
  int i = blockIdx.x * blockDim.x + threadIdx.x;
  if (i < V) deg[i] = 0;
  if (i < E) {
    int a = edges[i], b = edges[E + i];
    float ax = vs[2 * a], ay = vs[2 * a + 1];
    float bx = vs[2 * b], by = vs[2 * b + 1];
    const float eps = 1e-3f;
    const float hi = 1.0f - 1e-3f;
    bool ba = (ax < eps) || (ax > hi) || (ay < eps) || (ay > hi);
    bool bb = (bx < eps) || (bx > hi) || (by < eps) || (by > hi);
    elig[i] = (!ba && !bb) ? 1 : 0;
  }
}

// ---------------- build neighbor lists -------------------------------------
__global__ void k_lists(const int* __restrict__ edges, int E,
                        int* __restrict__ deg, unsigned short* __restrict__ nbr) {
  int e = blockIdx.x * blockDim.x + threadIdx.x;
  if (e >= E) return;
  int a = edges[e], b = edges[E + e];
  int ia = atomicAdd(&deg[a], 1);
  nbr[a * CAP + ia] = (unsigned short)b;
  int ib = atomicAdd(&deg[b], 1);
  nbr[b * CAP + ib] = (unsigned short)a;
}

// ---------------- sortable keys: prio(double) top bits | edge id -----------
__global__ void k_keys(const double* __restrict__ sqd, const int* __restrict__ edges,
                       int E, int P, u64* __restrict__ keys) {
  int e = blockIdx.x * blockDim.x + threadIdx.x;
  if (e >= P) return;
  if (e < E) {
    double prio = sqd[edges[e]] + sqd[edges[E + e]];
    u64 bits = (u64)__double_as_longlong(prio);  // prio > 0 -> bits monotone
    keys[e] = (bits & ~0xFFFFull) | (u64)e;
  } else {
    keys[e] = ~0ull;
  }
}

// ---------------- single-block bitonic sort, LDS-staged --------------------
#define SCH 4096
__global__ void __launch_bounds__(1024)
k_sort(u64* __restrict__ keys, int n) {
  __shared__ u64 buf[SCH];
  int tid = threadIdx.x;
  int nt = blockDim.x;
  int ch = n < SCH ? n : SCH;
  for (int chunk = 0; chunk < n; chunk += ch) {
    for (int i = tid; i < ch; i += nt) buf[i] = keys[chunk + i];
    __syncthreads();
    for (int k = 2; k <= ch; k <<= 1) {
      for (int j = k >> 1; j > 0; j >>= 1) {
        for (int li = tid; li < ch; li += nt) {
          int lj = li ^ j;
          if (lj > li) {
            u64 x = buf[li], y = buf[lj];
            bool up = (((chunk + li) & k) == 0);
            if (up ? (x > y) : (x < y)) { buf[li] = y; buf[lj] = x; }
          }
        }
        __syncthreads();
      }
    }
    for (int i = tid; i < ch; i += nt) keys[chunk + i] = buf[i];
    __syncthreads();
  }
  for (int k = (ch << 1); k <= n; k <<= 1) {
    for (int j = k >> 1; j >= ch; j >>= 1) {
      for (int i = tid; i < n; i += nt) {
        int ixj = i ^ j;
        if (ixj > i) {
          u64 x = keys[i], y = keys[ixj];
          bool up = ((i & k) == 0);
          if (up ? (x > y) : (x < y)) { keys[i] = y; keys[ixj] = x; }
        }
      }
      __syncthreads();
    }
    for (int chunk = 0; chunk < n; chunk += ch) {
      for (int i = tid; i < ch; i += nt) buf[i] = keys[chunk + i];
      __syncthreads();
      for (int j = ch >> 1; j > 0; j >>= 1) {
        for (int li = tid; li < ch; li += nt) {
          int lj = li ^ j;
          if (lj > li) {
            u64 x = buf[li], y = buf[lj];
            bool up = (((chunk + li) & k) == 0);
            if (up ? (x > y) : (x < y)) { buf[li] = y; buf[lj] = x; }
          }
        }
        __syncthreads();
      }
      for (int i = tid; i < ch; i += nt) keys[chunk + i] = buf[i];
      __syncthreads();
    }
  }
}

// ---------------- gather sorted (v0,v1,elig) into one packed word ----------
__global__ void k_reorder(const u64* __restrict__ keys, const int* __restrict__ edges,
                          const unsigned char* __restrict__ elig, int E,
                          unsigned* __restrict__ packed) {
  int t = blockIdx.x * blockDim.x + threadIdx.x;
  if (t >= E) return;
  int eid = (int)(keys[t] & 0xFFFFull);
  unsigned v0 = (unsigned)edges[eid];
  unsigned v1 = (unsigned)edges[E + eid];
  unsigned el = (unsigned)elig[eid];
  packed[t] = v0 | (v1 << 14) | (el << 28);
}

// ---------------- sequential greedy decimation (single wave) ---------------
// Eager-clean sparse rows: nbr[v] always holds exactly the live neighbor set.
// Eval: grouped prefetch + plain-write u16 mark arrays (distinct addresses,
// no atomics) -> one LDS round trip for membership. Commit: rewrite row(v0)
// from registers; per-lane fixups of rows of N(v1); touch[] seq invalidates
// prefetched copies.
__global__ void __launch_bounds__(64, 1)
k_decimate(int E, int V, int target, const unsigned* __restrict__ packed,
           const int* __restrict__ deg_g, unsigned short* __restrict__ nbr,
           int2* __restrict__ events, int* __restrict__ nev_out) {
  __shared__ unsigned short degs[MAXV];
  __shared__ unsigned short touch[MAXV];
  __shared__ unsigned short markA[MAXV];
  __shared__ unsigned short markB[MAXV];
  const int lane = threadIdx.x;
  if (V > MAXV) return;
  for (int v = lane; v < V; v += 64) {
    degs[v] = (unsigned short)deg_g[v];
    touch[v] = 0; markA[v] = 0; markB[v] = 0;
  }
  __syncthreads();

  int count = V, nev = 0;
  unsigned tag = 0;
  bool stop = false;
  bool dirty = false;           // stores pending since last vmcnt(0) drain
  const u64 lanebit = 1ull << lane;
  const u64 below = lanebit - 1;

  for (int base = 0; base < E && !stop; base += 64) {
    int t = base + lane;
    unsigned pk = (t < E) ? packed[t] : 0u;
    int mv0 = (int)(pk & 0x3FFFu);
    int mv1 = (int)((pk >> 14) & 0x3FFFu);
    bool cand = (t < E) && ((pk >> 28) & 1u) && degs[mv0] > 0 && degs[mv1] > 0;
    u64 cm = __ballot(cand);

    while (cm != 0 && !stop) {
      int ids[GD], gv0[GD], gv1[GD];
      unsigned ga[GD], gb[GD];
#pragma unroll
      for (int g = 0; g < GD; ++g) {
        if (cm) { ids[g] = __builtin_ctzll(cm); cm &= cm - 1; } else ids[g] = -1;
      }
      if (dirty) {              // group loads must see all prior commit stores
        asm volatile("s_waitcnt vmcnt(0)" ::: "memory");
        __builtin_amdgcn_sched_barrier(0);
        dirty = false;
      }
      int groupSeq = nev;
#pragma unroll
      for (int g = 0; g < GD; ++g) {
        if (ids[g] >= 0) {
          unsigned pkc = __builtin_amdgcn_readlane(pk, ids[g]);
          gv0[g] = (int)(pkc & 0x3FFFu);
          gv1[g] = (int)((pkc >> 14) & 0x3FFFu);
          ga[g] = (unsigned)nbr[gv0[g] * CAP + lane];
          gb[g] = (unsigned)nbr[gv1[g] * CAP + lane];
        } else { gv0[g] = -1; gv1[g] = -1; ga[g] = 0; gb[g] = 0; }
      }

#pragma unroll
      for (int g = 0; g < GD; ++g) {
        if (gv0[g] < 0 || stop) continue;
        int cv0 = gv0[g], cv1 = gv1[g];
        int d0 = degs[cv0], d1 = degs[cv1];
        if (d0 == 0 || d1 == 0) continue;            // died earlier
        if (touch[cv0] > groupSeq || touch[cv1] > groupSeq) {
          // prefetched copy predates an in-group commit: drain + reload
          asm volatile("s_waitcnt vmcnt(0)" ::: "memory");
          __builtin_amdgcn_sched_barrier(0);
          dirty = false;
          ga[g] = (unsigned)nbr[cv0 * CAP + lane];
          gb[g] = (unsigned)nbr[cv1 * CAP + lane];
        }
        unsigned aa = ga[g], bb = gb[g];
        bool valid0 = lane < d0, valid1 = lane < d1;

        // O(1) membership via plain-write versioned marks (rows are clean:
        // entries distinct -> no same-address writes -> deterministic)
        ++tag;
        if (valid0) markA[aa] = (unsigned short)tag;
        if (valid1) markB[bb] = (unsigned short)tag;
        asm volatile("s_waitcnt lgkmcnt(0)" ::: "memory");
        __builtin_amdgcn_sched_barrier(0);
        bool aInB = valid0 && (markB[aa] == (unsigned short)tag);
        bool bInA = valid1 && (markA[bb] == (unsigned short)tag);
        if (__popcll(__ballot(aInB)) != 2) continue;

        // ---- commit merge cv1 -> cv0 ----
        unsigned short seq = (unsigned short)(nev + 1);
        u64 keepMask = __ballot(valid0 && aa != (unsigned)cv1);
        u64 addMask  = __ballot(valid1 && bb != (unsigned)cv0 && !bInA);
        int nKeep = __popcll(keepMask);
        int newd  = nKeep + __popcll(addMask);
        if (newd > CAP) newd = CAP;
        if (keepMask & lanebit)
          nbr[cv0 * CAP + __popcll(keepMask & below)] = (unsigned short)aa;
        if (addMask & lanebit) {
          int pos = nKeep + __popcll(addMask & below);
          if (pos < CAP) nbr[cv0 * CAP + pos] = (unsigned short)bb;
        }

        // u-row fixups must see prior in-group commits' stores
        asm volatile("s_waitcnt vmcnt(0)" ::: "memory");
        __builtin_amdgcn_sched_barrier(0);

        // fix rows of u in N(v1)\{v0}: drop v1 if v0 already there, else v1->v0
        bool doU = valid1 && (bb != (unsigned)cv0);
        if (doU) {
          int u = (int)bb;
          int du = degs[u];
          const uint4* rowp = (const uint4*)(nbr + u * CAP);
          unsigned tg = (unsigned)cv1;
          int posv1 = -1;
          unsigned lastv = 0;
          int li = du - 1;
          int nw = (du + 7) >> 3;
          for (int c = 0; c < nw; ++c) {
            uint4 w = rowp[c];
            int b8 = c << 3;
            if ((w.x & 0xFFFFu) == tg && b8 + 0 < du) posv1 = b8 + 0;
            if ((w.x >> 16)     == tg && b8 + 1 < du) posv1 = b8 + 1;
            if ((w.y & 0xFFFFu) == tg && b8 + 2 < du) posv1 = b8 + 2;
            if ((w.y >> 16)     == tg && b8 + 3 < du) posv1 = b8 + 3;
            if ((w.z & 0xFFFFu) == tg && b8 + 4 < du) posv1 = b8 + 4;
            if ((w.z >> 16)     == tg && b8 + 5 < du) posv1 = b8 + 5;
            if ((w.w & 0xFFFFu) == tg && b8 + 6 < du) posv1 = b8 + 6;
            if ((w.w >> 16)     == tg && b8 + 7 < du) posv1 = b8 + 7;
            if ((li >> 3) == c) {
              int k = li & 7;
              unsigned wd = (k < 2) ? w.x : (k < 4) ? w.y : (k < 6) ? w.z : w.w;
              lastv = (k & 1) ? (wd >> 16) : (wd & 0xFFFFu);
            }
          }
          if (posv1 >= 0) {
            if (bInA) {            // v0 already neighbor of u: remove v1
              if (posv1 != li) nbr[u * CAP + posv1] = (unsigned short)lastv;
              degs[u] = (unsigned short)(du - 1);
            } else {               // replace v1 by v0
              nbr[u * CAP + posv1] = (unsigned short)cv0;
            }
          }
          touch[u] = seq;
        }
        if (lane == 0) {
          touch[cv0] = seq;
          degs[cv0] = (unsigned short)newd;
          degs[cv1] = 0;
          events[nev] = make_int2(cv0, cv1);
        }
        asm volatile("s_waitcnt lgkmcnt(0)" ::: "memory");
        __builtin_amdgcn_sched_barrier(0);
        dirty = true;
        nev++;
        count--;
        if (count <= target) stop = true;
      }
    }
  }
  if (lane == 0) nev_out[0] = nev;
}

// ---------------- reverse-replay: owner + weight per original vertex -------
__global__ void __launch_bounds__(256)
k_weights(const int2* __restrict__ events, const int* __restrict__ nev_p,
          int V, int* __restrict__ own, float* __restrict__ wgt) {
  __shared__ int O[MAXV];
  __shared__ unsigned short H[MAXV];
  __shared__ int2 evb[256];
  int tid = threadIdx.x;
  if (V > MAXV) return;
  for (int v = tid; v < V; v += blockDim.x) { O[v] = v; H[v] = 0; }
  int n = nev_p[0];
  __syncthreads();
  int nb = (n + 255) >> 8;
  for (int b = nb - 1; b >= 0; --b) {
    int bbase = b << 8;
    int cnt = n - bbase; if (cnt > 256) cnt = 256;
    if (tid < cnt) evb[tid] = events[bbase + tid];
    __syncthreads();
    if (tid == 0) {
      for (int k = cnt - 1; k >= 0; --k) {
        int2 ev = evb[k];
        int h = (int)H[ev.x] + 1;
        H[ev.x] = (unsigned short)h;
        H[ev.y] = (unsigned short)h;
        O[ev.y] = O[ev.x];
      }
    }
    __syncthreads();
  }
  for (int v = tid; v < V; v += blockDim.x) {
    own[v] = O[v];
    wgt[v] = ldexpf(1.0f, -(int)H[v]);
  }
}

// ---------------- output ---------------------------------------------------
__global__ void k_zero(float4* __restrict__ out, int n4) {
  int i = blockIdx.x * blockDim.x + threadIdx.x;
  if (i < n4) out[i] = make_float4(0.f, 0.f, 0.f, 0.f);
}

__global__ void k_scatter(const float* __restrict__ img, const int* __restrict__ own,
                          const float* __restrict__ wgt, float* __restrict__ out, int V) {
  int v = blockIdx.x;
  if (v >= V) return;
  float w = wgt[v];
  int o = own[v];
  const float* src = img + (size_t)v * F_DIM;
  float* dst = out + (size_t)o * F_DIM;
  if (w == 1.0f) {
    for (int f = threadIdx.x; f < F_DIM; f += blockDim.x) dst[f] = src[f];
  } else {
    for (int f = threadIdx.x; f < F_DIM; f += blockDim.x) atomicAdd(&dst[f], w * src[f]);
  }
}

extern "C" void kernel_launch(void* const* d_in, const int* in_sizes, int n_in,
                              void* d_out, int out_size, void* d_ws, size_t ws_size,
                              hipStream_t stream) {
  const float* img  = (const float*)d_in[0];
  const int* edges  = (const int*)d_in[1];
  const float* vs   = (const float*)d_in[2];
  int V = in_sizes[2] / 2;
  int E = in_sizes[1] / 2;
  int P = 1; while (P < E) P <<= 1;

  char* wsp = (char*)d_ws;
  size_t off = 0;
  auto alloc = [&](size_t bytes) -> void* {
    void* p = (void*)(wsp + off);
    off = (off + bytes + 255) & ~(size_t)255;
    return p;
  };
  double* sqd          = (double*)alloc((size_t)V * 8);
  u64* keys            = (u64*)alloc((size_t)P * 8);
  int* deg             = (int*)alloc((size_t)V * 4);
  unsigned short* nbr  = (unsigned short*)alloc((size_t)V * CAP * 2 + 256);
  unsigned char* elig  = (unsigned char*)alloc((size_t)E);
  unsigned* packed     = (unsigned*)alloc((size_t)E * 4);
  int2* events         = (int2*)alloc((size_t)(V / 2 + 64) * 8);
  int* nev             = (int*)alloc(256);
  int* own             = (int*)alloc((size_t)V * 4);
  float* wgt           = (float*)alloc((size_t)V * 4);

  hipLaunchKernelGGL(k_sq, dim3(V), dim3(64), 0, stream, img, sqd, V);
  int mx = V > E ? V : E;
  hipLaunchKernelGGL(k_prep, dim3((mx + 255) / 256), dim3(256), 0, stream, vs, edges, V, E, deg, elig);
  hipLaunchKernelGGL(k_lists, dim3((E + 255) / 256), dim3(256), 0, stream, edges, E, deg, nbr);
  hipLaunchKernelGGL(k_keys, dim3((P + 255) / 256), dim3(256), 0, stream, sqd, edges, E, P, keys);
  hipLaunchKernelGGL(k_sort, dim3(1), dim3(1024), 0, stream, keys, P);
  hipLaunchKernelGGL(k_reorder, dim3((E + 255) / 256), dim3(256), 0, stream, keys, edges, elig, E, packed);
  hipLaunchKernelGGL(k_decimate, dim3(1), dim3(64), 0, stream,
                     E, V, V / 2, packed, deg, nbr, events, nev);
  hipLaunchKernelGGL(k_weights, dim3(1), dim3(256), 0, stream, events, nev, V, own, wgt);
  int n4 = (V * F_DIM) / 4;
  hipLaunchKernelGGL(k_zero, dim3((n4 + 255) / 256), dim3(256), 0, stream, (float4*)d_out, n4);
  hipLaunchKernelGGL(k_scatter, dim3(V), dim3(256), 0, stream, img, own, wgt, (float*)d_out, V);
}